// Round 7
// baseline (815.906 us; speedup 1.0000x reference)
//
#include <hip/hip_runtime.h>
#include <cstddef>
#include <cstdint>

// ---------------------------------------------------------------------------
// SAGE_89429809037918: pre-Linear(128->128) -> SAGEConv(128->256)+ReLU
//   -> SAGEConv(256->256)+ReLU -> SAGEConv(256->256) -> row L2-normalize.
// R6: gather rework — degree-sorted node order (block-level load balance;
//     Poisson(16) degrees made a 4-wave block wait on E[max of 4] ~ 25 vs
//     mean 16) + 16B/lane uint4 loads with half-wave row split (2x MLP).
//     bf16+MFMA GEMM pipeline unchanged from R5 (547.9 us).
// ---------------------------------------------------------------------------

typedef __attribute__((ext_vector_type(8))) short short8;   // 8 bf16 = 4 VGPR
typedef __attribute__((ext_vector_type(4))) float f32x4;

__device__ __forceinline__ unsigned rne_bf16(float f) {
    unsigned b = __float_as_uint(f);
    return (b + 0x7fffu + ((b >> 16) & 1u)) >> 16;
}
__device__ __forceinline__ float bf16_lo(unsigned u) { return __uint_as_float(u << 16); }
__device__ __forceinline__ float bf16_hi(unsigned u) { return __uint_as_float(u & 0xffff0000u); }

__device__ __forceinline__ void add8(float* a, uint4 u) {
    a[0] += bf16_lo(u.x); a[1] += bf16_hi(u.x);
    a[2] += bf16_lo(u.y); a[3] += bf16_hi(u.y);
    a[4] += bf16_lo(u.z); a[5] += bf16_hi(u.z);
    a[6] += bf16_lo(u.w); a[7] += bf16_hi(u.w);
}

// ---------------- counting sort: histogram -> scan -> fill ----------------

__global__ __launch_bounds__(256) void deg_kernel(const int* __restrict__ dst,
                                                  int* __restrict__ deg, int E) {
    int e = blockIdx.x * 256 + threadIdx.x;
    if (e < E) atomicAdd(&deg[dst[e]], 1);
}

__global__ __launch_bounds__(256) void bsum_kernel(const int* __restrict__ deg,
                                                   int* __restrict__ bsum, int n) {
    int i = blockIdx.x * 256 + threadIdx.x;
    int v = (i < n) ? deg[i] : 0;
#pragma unroll
    for (int s = 32; s > 0; s >>= 1) v += __shfl_down(v, s);
    __shared__ int ws[4];
    int lane = threadIdx.x & 63, w = threadIdx.x >> 6;
    if (lane == 0) ws[w] = v;
    __syncthreads();
    if (threadIdx.x == 0) bsum[blockIdx.x] = ws[0] + ws[1] + ws[2] + ws[3];
}

__global__ __launch_bounds__(256) void bscan_kernel(const int* __restrict__ bsum,
                                                    int* __restrict__ boff,
                                                    int* __restrict__ off,
                                                    int nb, int n, int E) {
    int t = threadIdx.x;
    int v = (t < nb) ? bsum[t] : 0;
    int incl = v;
#pragma unroll
    for (int s = 1; s < 64; s <<= 1) {
        int u = __shfl_up(incl, s);
        if ((t & 63) >= s) incl += u;
    }
    __shared__ int ws[4];
    int lane = t & 63, w = t >> 6;
    if (lane == 63) ws[w] = incl;
    __syncthreads();
    int woff = 0;
    for (int j = 0; j < w; ++j) woff += ws[j];
    if (t < nb) boff[t] = woff + incl - v;
    if (t == 0) off[n] = E;
}

__global__ __launch_bounds__(256) void scan_kernel(const int* __restrict__ deg,
                                                   const int* __restrict__ boff,
                                                   int* __restrict__ off,
                                                   float* __restrict__ inv, int n) {
    int i = blockIdx.x * 256 + threadIdx.x;
    int v = (i < n) ? deg[i] : 0;
    int incl = v;
#pragma unroll
    for (int s = 1; s < 64; s <<= 1) {
        int u = __shfl_up(incl, s);
        if ((threadIdx.x & 63) >= s) incl += u;
    }
    __shared__ int ws[4];
    int lane = threadIdx.x & 63, w = threadIdx.x >> 6;
    if (lane == 63) ws[w] = incl;
    __syncthreads();
    int woff = 0;
    for (int j = 0; j < w; ++j) woff += ws[j];
    if (i < n) {
        off[i] = boff[blockIdx.x] + woff + incl - v;
        inv[i] = 1.0f / fmaxf((float)v, 1.0f);
    }
}

__global__ __launch_bounds__(256) void fill_kernel(const int* __restrict__ src,
                                                   const int* __restrict__ dst,
                                                   const int* __restrict__ off,
                                                   int* __restrict__ deg,
                                                   int* __restrict__ ssrc, int E) {
    int e = blockIdx.x * 256 + threadIdx.x;
    if (e >= E) return;
    int d = dst[e];
    int pos = off[d] + atomicSub(&deg[d], 1) - 1;
    ssrc[pos] = src[e];
}

// ---------------- degree-sort: nodeperm = nodes ordered by degree ----------

__global__ __launch_bounds__(256) void dhist_kernel(const int* __restrict__ off,
                                                    int* __restrict__ hist, int n) {
    int v = blockIdx.x * 256 + threadIdx.x;
    if (v < n) atomicAdd(&hist[min(off[v + 1] - off[v], 1023)], 1);
}

// single-block exclusive scan of hist[1024] -> doff[1024] (4 per thread)
__global__ __launch_bounds__(256) void dscan_kernel(const int* __restrict__ hist,
                                                    int* __restrict__ doff) {
    int t = threadIdx.x;
    int s0 = hist[t * 4], s1 = hist[t * 4 + 1], s2 = hist[t * 4 + 2], s3 = hist[t * 4 + 3];
    int sum = s0 + s1 + s2 + s3;
    int incl = sum;
#pragma unroll
    for (int s = 1; s < 64; s <<= 1) {
        int u = __shfl_up(incl, s);
        if ((t & 63) >= s) incl += u;
    }
    __shared__ int ws[4];
    int lane = t & 63, w = t >> 6;
    if (lane == 63) ws[w] = incl;
    __syncthreads();
    int woff = 0;
    for (int j = 0; j < w; ++j) woff += ws[j];
    int base = woff + incl - sum;
    doff[t * 4]     = base;
    doff[t * 4 + 1] = base + s0;
    doff[t * 4 + 2] = base + s0 + s1;
    doff[t * 4 + 3] = base + s0 + s1 + s2;
}

__global__ __launch_bounds__(256) void dfill_kernel(const int* __restrict__ off,
                                                    int* __restrict__ doff,
                                                    int* __restrict__ perm, int n) {
    int v = blockIdx.x * 256 + threadIdx.x;
    if (v >= n) return;
    int d = min(off[v + 1] - off[v], 1023);
    perm[atomicAdd(&doff[d], 1)] = v;
}

// ---------------- one-shot converts: x -> bf16, W -> bf16 transposed --------

__global__ __launch_bounds__(256) void xconv(const float* __restrict__ x,
                                             uint2* __restrict__ xb, int n4) {
    int i = blockIdx.x * 256 + threadIdx.x;
    if (i >= n4) return;
    float4 v = ((const float4*)x)[i];
    uint2 o;
    o.x = rne_bf16(v.x) | (rne_bf16(v.y) << 16);
    o.y = rne_bf16(v.z) | (rne_bf16(v.w) << 16);
    xb[i] = o;
}

// W [K][Nn] fp32 -> WT [Nn][K] bf16, for all 7 weight matrices in one launch
__global__ __launch_bounds__(256) void wprep(
    const float* __restrict__ pre_W, const float* __restrict__ W1_l,
    const float* __restrict__ W1_r, const float* __restrict__ W2_l,
    const float* __restrict__ W2_r, const float* __restrict__ W3_l,
    const float* __restrict__ W3_r,
    unsigned short* __restrict__ WT0, unsigned short* __restrict__ WT1,
    unsigned short* __restrict__ WT2, unsigned short* __restrict__ WT3,
    unsigned short* __restrict__ WT4, unsigned short* __restrict__ WT5,
    unsigned short* __restrict__ WT6) {
    int idx = blockIdx.x * 256 + threadIdx.x;
    if (idx < 16384) {  // pre_W 128x128
        int k = idx >> 7, n = idx & 127;
        WT0[n * 128 + k] = (unsigned short)rne_bf16(pre_W[idx]);
        return;
    }
    idx -= 16384;
    if (idx < 32768) {  // W1_l 128x256
        int k = idx >> 8, n = idx & 255;
        WT1[n * 128 + k] = (unsigned short)rne_bf16(W1_l[idx]);
        return;
    }
    idx -= 32768;
    if (idx < 32768) {  // W1_r 128x256
        int k = idx >> 8, n = idx & 255;
        WT2[n * 128 + k] = (unsigned short)rne_bf16(W1_r[idx]);
        return;
    }
    idx -= 32768;
    if (idx < 65536) {  // W2_l 256x256
        int k = idx >> 8, n = idx & 255;
        WT3[n * 256 + k] = (unsigned short)rne_bf16(W2_l[idx]);
        return;
    }
    idx -= 65536;
    if (idx < 65536) {  // W2_r
        int k = idx >> 8, n = idx & 255;
        WT4[n * 256 + k] = (unsigned short)rne_bf16(W2_r[idx]);
        return;
    }
    idx -= 65536;
    if (idx < 65536) {  // W3_l
        int k = idx >> 8, n = idx & 255;
        WT5[n * 256 + k] = (unsigned short)rne_bf16(W3_l[idx]);
        return;
    }
    idx -= 65536;
    if (idx < 65536) {  // W3_r
        int k = idx >> 8, n = idx & 255;
        WT6[n * 256 + k] = (unsigned short)rne_bf16(W3_r[idx]);
    }
}

// ---------------- gather aggregation, degree-sorted, 16B/lane ---------------
// D=256: half-wave row split — lanes 0-31 row k, lanes 32-63 row k+1, x2 unroll.
__global__ __launch_bounds__(256) void gather256(const unsigned short* __restrict__ h,
                                                 const int* __restrict__ off,
                                                 const int* __restrict__ ssrc,
                                                 const float* __restrict__ inv,
                                                 const int* __restrict__ perm,
                                                 unsigned short* __restrict__ agg, int n) {
    int idx = blockIdx.x * 4 + (threadIdx.x >> 6);
    if (idx >= n) return;
    int node = perm[idx];
    int lane = threadIdx.x & 63;
    int half = lane >> 5;
    int c = (lane & 31) << 3;        // column base: 8 bf16 (16 B) per lane
    int beg = off[node], end = off[node + 1];
    float sc = inv[node];
    const unsigned short* colp = h + c;

    float a[8] = {0, 0, 0, 0, 0, 0, 0, 0};
    float b[8] = {0, 0, 0, 0, 0, 0, 0, 0};
    int k = beg;
    for (; k + 3 < end; k += 4) {
        int sA = ssrc[k + half];
        int sB = ssrc[k + 2 + half];
        uint4 u = *(const uint4*)(colp + (size_t)sA * 256);
        uint4 v = *(const uint4*)(colp + (size_t)sB * 256);
        add8(a, u);
        add8(b, v);
    }
    if (k + 1 < end) {               // pair
        uint4 u = *(const uint4*)(colp + (size_t)ssrc[k + half] * 256);
        add8(a, u);
        k += 2;
    }
    if (k < end && half == 0) {      // single leftover, low half only
        uint4 u = *(const uint4*)(colp + (size_t)ssrc[k] * 256);
        add8(a, u);
    }
#pragma unroll
    for (int i = 0; i < 8; ++i) {
        a[i] += b[i];
        a[i] += __shfl_xor(a[i], 32);
        a[i] *= sc;
    }
    if (half == 0) {
        uint4 o;
        o.x = rne_bf16(a[0]) | (rne_bf16(a[1]) << 16);
        o.y = rne_bf16(a[2]) | (rne_bf16(a[3]) << 16);
        o.z = rne_bf16(a[4]) | (rne_bf16(a[5]) << 16);
        o.w = rne_bf16(a[6]) | (rne_bf16(a[7]) << 16);
        *(uint4*)(agg + (size_t)node * 256 + c) = o;
    }
}

// D=128: quarter-wave row split — quarter q handles row k+q, x2 unroll.
__global__ __launch_bounds__(256) void gather128(const unsigned short* __restrict__ h,
                                                 const int* __restrict__ off,
                                                 const int* __restrict__ ssrc,
                                                 const float* __restrict__ inv,
                                                 const int* __restrict__ perm,
                                                 unsigned short* __restrict__ agg, int n) {
    int idx = blockIdx.x * 4 + (threadIdx.x >> 6);
    if (idx >= n) return;
    int node = perm[idx];
    int lane = threadIdx.x & 63;
    int q = lane >> 4;
    int c = (lane & 15) << 3;        // 8 bf16 per lane, 16 lanes = 128 cols
    int beg = off[node], end = off[node + 1];
    float sc = inv[node];
    const unsigned short* colp = h + c;

    float a[8] = {0, 0, 0, 0, 0, 0, 0, 0};
    float b[8] = {0, 0, 0, 0, 0, 0, 0, 0};
    int k = beg;
    for (; k + 7 < end; k += 8) {
        int sA = ssrc[k + q];
        int sB = ssrc[k + 4 + q];
        uint4 u = *(const uint4*)(colp + (size_t)sA * 128);
        uint4 v = *(const uint4*)(colp + (size_t)sB * 128);
        add8(a, u);
        add8(b, v);
    }
    if (k + 3 < end) {
        uint4 u = *(const uint4*)(colp + (size_t)ssrc[k + q] * 128);
        add8(a, u);
        k += 4;
    }
    if (q < end - k) {               // tail 0..3 rows
        uint4 u = *(const uint4*)(colp + (size_t)ssrc[k + q] * 128);
        add8(a, u);
    }
#pragma unroll
    for (int i = 0; i < 8; ++i) {
        a[i] += b[i];
        a[i] += __shfl_xor(a[i], 32);
        a[i] += __shfl_xor(a[i], 16);
        a[i] *= sc;
    }
    if (q == 0) {
        uint4 o;
        o.x = rne_bf16(a[0]) | (rne_bf16(a[1]) << 16);
        o.y = rne_bf16(a[2]) | (rne_bf16(a[3]) << 16);
        o.z = rne_bf16(a[4]) | (rne_bf16(a[5]) << 16);
        o.w = rne_bf16(a[6]) | (rne_bf16(a[7]) << 16);
        *(uint4*)(agg + (size_t)node * 128 + c) = o;
    }
}

// ---------------- MFMA GEMM: out = act(A1@W1T^T + bias + A2@W2T^T) ---------
// A row-major bf16 [M,K]; WT row-major bf16 [Nn,K]. Block tile 128x128,
// 4 waves 2x2 (64x64/wave), BK=64. XOR-swizzled LDS (slot s of row r holds
// global chunk s^(r&7)) keeps ds_read_b128 <=2-way. VGPR staging.
__global__ __launch_bounds__(256) void gemm_bt(
    const unsigned short* __restrict__ A1, const unsigned short* __restrict__ W1T,
    const unsigned short* __restrict__ A2, const unsigned short* __restrict__ W2T,
    const float* __restrict__ bias,
    unsigned short* __restrict__ outb, float* __restrict__ outf,
    int M, int K, int Nn, int relu) {
    __shared__ __align__(16) unsigned short As[128 * 64];
    __shared__ __align__(16) unsigned short Bs[128 * 64];

    const int t = threadIdx.x;
    const int lane = t & 63;
    const int w = t >> 6;
    const int wm = w >> 1, wn = w & 1;
    const int m0 = blockIdx.x * 128;
    const int n0 = blockIdx.y * 128;

    f32x4 acc[4][4];
#pragma unroll
    for (int i = 0; i < 4; ++i)
#pragma unroll
        for (int j = 0; j < 4; ++j) acc[i][j] = (f32x4){0.f, 0.f, 0.f, 0.f};

    for (int pass = 0; pass < 2; ++pass) {
        const unsigned short* A = pass ? A2 : A1;
        const unsigned short* W = pass ? W2T : W1T;
        if (pass && A2 == nullptr) break;

        for (int k0 = 0; k0 < K; k0 += 64) {
#pragma unroll
            for (int r = 0; r < 4; ++r) {
                int p = r * 256 + t;          // LDS 16B-chunk index 0..1023
                int row = p >> 3, slot = p & 7;
                int c = slot ^ (row & 7);     // which global chunk lands here
                int gm = m0 + row;
                if (gm >= M) gm = M - 1;      // clamp; result rows >=M discarded
                uint4 va = *(const uint4*)(A + (size_t)gm * K + k0 + c * 8);
                uint4 vb = *(const uint4*)(W + (size_t)(n0 + row) * K + k0 + c * 8);
                *(uint4*)&As[(size_t)p * 8] = va;
                *(uint4*)&Bs[(size_t)p * 8] = vb;
            }
            __syncthreads();
#pragma unroll
            for (int kk = 0; kk < 2; ++kk) {
                short8 af[4], bfr[4];
                int ac = kk * 4 + (lane >> 4);
#pragma unroll
                for (int i = 0; i < 4; ++i) {
                    int arow = wm * 64 + i * 16 + (lane & 15);
                    af[i] = *(const short8*)&As[arow * 64 + ((ac ^ (arow & 7)) << 3)];
                    int brow = wn * 64 + i * 16 + (lane & 15);
                    bfr[i] = *(const short8*)&Bs[brow * 64 + ((ac ^ (brow & 7)) << 3)];
                }
#pragma unroll
                for (int mi = 0; mi < 4; ++mi)
#pragma unroll
                    for (int ni = 0; ni < 4; ++ni)
                        acc[mi][ni] = __builtin_amdgcn_mfma_f32_16x16x32_bf16(
                            af[mi], bfr[ni], acc[mi][ni], 0, 0, 0);
            }
            __syncthreads();
        }
    }

    // epilogue: C/D layout col(n)=lane&15, row(m)=(lane>>4)*4+reg
#pragma unroll
    for (int ni = 0; ni < 4; ++ni) {
        int n = n0 + wn * 64 + ni * 16 + (lane & 15);
        float bv = (bias != nullptr) ? bias[n] : 0.0f;
#pragma unroll
        for (int mi = 0; mi < 4; ++mi) {
            int mbase = m0 + wm * 64 + mi * 16 + ((lane >> 4) << 2);
#pragma unroll
            for (int r = 0; r < 4; ++r) {
                int m = mbase + r;
                if (m >= M) continue;
                float v = acc[mi][ni][r] + bv;
                if (relu) v = fmaxf(v, 0.0f);
                if (outb) outb[(size_t)m * Nn + n] = (unsigned short)rne_bf16(v);
                else      outf[(size_t)m * Nn + n] = v;
            }
        }
    }
}

// row-wise L2 normalize, rows of 256 floats; 4 rows per 256-thread block
__global__ __launch_bounds__(256) void norm_kernel(float* __restrict__ out, int M) {
    int row  = blockIdx.x * 4 + (threadIdx.x >> 6);
    int lane = threadIdx.x & 63;
    if (row >= M) return;
    float4 v = *(float4*)(out + (size_t)row * 256 + (lane << 2));
    float s = v.x * v.x + v.y * v.y + v.z * v.z + v.w * v.w;
#pragma unroll
    for (int off = 32; off > 0; off >>= 1) s += __shfl_down(s, off);
    s = __shfl(s, 0);
    float scale = 1.0f / fmaxf(sqrtf(s), 1e-12f);
    v.x *= scale; v.y *= scale; v.z *= scale; v.w *= scale;
    *(float4*)(out + (size_t)row * 256 + (lane << 2)) = v;
}

extern "C" void kernel_launch(void* const* d_in, const int* in_sizes, int n_in,
                              void* d_out, int out_size, void* d_ws, size_t ws_size,
                              hipStream_t stream) {
    const int N = 50000;
    const int E = 800000;
    const int NB = (N + 255) / 256;

    const float* x     = (const float*)d_in[0];
    const int*   ei    = (const int*)d_in[1];
    const float* pre_W = (const float*)d_in[2];
    const float* pre_b = (const float*)d_in[3];
    const float* W1_l  = (const float*)d_in[4];
    const float* b1    = (const float*)d_in[5];
    const float* W1_r  = (const float*)d_in[6];
    const float* W2_l  = (const float*)d_in[7];
    const float* b2    = (const float*)d_in[8];
    const float* W2_r  = (const float*)d_in[9];
    const float* W3_l  = (const float*)d_in[10];
    const float* b3    = (const float*)d_in[11];
    const float* W3_r  = (const float*)d_in[12];
    float* out = (float*)d_out;

    const int* src = ei;
    const int* dst = ei + E;

    // ---- workspace layout ----
    int* deg  = (int*)d_ws;
    int* off  = deg + N;
    int* bsum = off + N + 1;
    int* boff = bsum + 256;
    int* hist = boff + 256;          // 1024
    int* doff = hist + 1024;         // 1024
    int* perm = doff + 1024;         // N
    int* ssrc = perm + N;            // E
    size_t int_words = (size_t)3 * N + 1 + 512 + 2048 + E;
    int_words = (int_words + 3) & ~(size_t)3;  // 16B align

    float* inv = (float*)d_ws + int_words;
    unsigned short* us = (unsigned short*)(inv + N);

    unsigned short* xb  = us;                 us += (size_t)N * 128;
    unsigned short* WT0 = us;                 us += 16384;
    unsigned short* WT1 = us;                 us += 32768;
    unsigned short* WT2 = us;                 us += 32768;
    unsigned short* WT3 = us;                 us += 65536;
    unsigned short* WT4 = us;                 us += 65536;
    unsigned short* WT5 = us;                 us += 65536;
    unsigned short* WT6 = us;                 us += 65536;
    unsigned short* h0b   = us;               us += (size_t)N * 128;
    unsigned short* agg1b = us;               us += (size_t)N * 128;
    unsigned short* h1b   = us;               us += (size_t)N * 256;
    unsigned short* agg2b = us;               us += (size_t)N * 256;
    unsigned short* h2b   = us;               us += (size_t)N * 256;
    unsigned short* agg3b = us;               us += (size_t)N * 256;

    // ---- build CSR (counting sort by dst) ----
    hipMemsetAsync(deg, 0, (size_t)N * sizeof(int), stream);
    hipMemsetAsync(hist, 0, 1024 * sizeof(int), stream);
    deg_kernel<<<(E + 255) / 256, 256, 0, stream>>>(dst, deg, E);
    bsum_kernel<<<NB, 256, 0, stream>>>(deg, bsum, N);
    bscan_kernel<<<1, 256, 0, stream>>>(bsum, boff, off, NB, N, E);
    scan_kernel<<<NB, 256, 0, stream>>>(deg, boff, off, inv, N);
    fill_kernel<<<(E + 255) / 256, 256, 0, stream>>>(src, dst, off, deg, ssrc, E);

    // ---- degree-sorted node permutation ----
    dhist_kernel<<<NB, 256, 0, stream>>>(off, hist, N);
    dscan_kernel<<<1, 256, 0, stream>>>(hist, doff);
    dfill_kernel<<<NB, 256, 0, stream>>>(off, doff, perm, N);

    // ---- converts ----
    xconv<<<(N * 128 / 4 + 255) / 256, 256, 0, stream>>>(x, (uint2*)xb, N * 128 / 4);
    wprep<<<(344064 + 255) / 256, 256, 0, stream>>>(pre_W, W1_l, W1_r, W2_l, W2_r,
                                                    W3_l, W3_r, WT0, WT1, WT2, WT3,
                                                    WT4, WT5, WT6);

    const int MT = (N + 127) / 128;  // 391
    const int AG = (N + 3) / 4;

    // ---- pre: h0 = x @ pre_W + pre_b ----
    gemm_bt<<<dim3(MT, 1), 256, 0, stream>>>(xb, WT0, nullptr, nullptr, pre_b,
                                             h0b, nullptr, N, 128, 128, 0);

    // ---- layer 1 ----
    gather128<<<AG, 256, 0, stream>>>(h0b, off, ssrc, inv, perm, agg1b, N);
    gemm_bt<<<dim3(MT, 2), 256, 0, stream>>>(agg1b, WT1, h0b, WT2, b1,
                                             h1b, nullptr, N, 128, 256, 1);

    // ---- layer 2 ----
    gather256<<<AG, 256, 0, stream>>>(h1b, off, ssrc, inv, perm, agg2b, N);
    gemm_bt<<<dim3(MT, 2), 256, 0, stream>>>(agg2b, WT3, h1b, WT4, b2,
                                             h2b, nullptr, N, 256, 256, 1);

    // ---- layer 3 (no relu), fp32 straight into d_out ----
    gather256<<<AG, 256, 0, stream>>>(h2b, off, ssrc, inv, perm, agg3b, N);
    gemm_bt<<<dim3(MT, 2), 256, 0, stream>>>(agg3b, WT5, h2b, WT6, b3,
                                             nullptr, out, N, 256, 256, 0);

    // ---- L2 normalize ----
    norm_kernel<<<AG, 256, 0, stream>>>(out, N);
}